// Round 12
// baseline (320.620 us; speedup 1.0000x reference)
//
#include <hip/hip_runtime.h>
#include <hip/hip_bf16.h>
#include <math.h>

#define N 8192
#define ZD 128
#define NTILE 64            // N / 128
#define NUPPER 2080         // NTILE*(NTILE+1)/2  (= 8 * 260, divisible by 8)

typedef __attribute__((ext_vector_type(8))) _Float16 f16x8;
typedef __attribute__((ext_vector_type(4))) float f32x4;

__device__ __forceinline__ int tri_cum(int ti) {   // tiles before row ti
    return (ti * (2 * NTILE + 1 - ti)) / 2;
}

__device__ __forceinline__ void tile_decode(int t, int& ti, int& tj) {
    int est = (int)((129.0f - sqrtf(16641.0f - 8.0f * (float)t)) * 0.5f);
    if (est < 0) est = 0;
    while (tri_cum(est) > t) --est;
    while (tri_cum(est + 1) <= t) ++est;
    ti = est;
    tj = est + (t - tri_cum(est));
}

// ---------------------------------------------------------------------------
// k1: Z = relu(h @ W1 + b1) @ W2 + b2 (fp32 math), stored as f16.
// Also initializes sums[i] = 1.0 (fill_diagonal contribution) every call.
// ---------------------------------------------------------------------------
__global__ __launch_bounds__(256) void k1_mlp(
    const float* __restrict__ h, const float* __restrict__ W1,
    const float* __restrict__ b1, const float* __restrict__ W2,
    const float* __restrict__ b2, _Float16* __restrict__ Zf,
    float* __restrict__ sums)
{
    __shared__ float W1s[64][65];
    __shared__ float W2s[64][129];
    __shared__ float hs[32][68];
    __shared__ float Ts[32][68];
    __shared__ float b1s[64];
    __shared__ float b2s[128];
    const int tid = threadIdx.x;
    const int row0 = blockIdx.x * 32;

    if (tid < 32) sums[row0 + tid] = 1.0f;

    for (int e = tid; e < 64 * 64; e += 256) W1s[e >> 6][e & 63] = W1[e];
    for (int e = tid; e < 64 * 128; e += 256) W2s[e >> 7][e & 127] = W2[e];
    for (int e = tid; e < 32 * 64; e += 256) hs[e >> 6][e & 63] = h[(size_t)row0 * 64 + e];
    if (tid < 64) b1s[tid] = b1[tid];
    if (tid < 128) b2s[tid] = b2[tid];
    __syncthreads();

    {
        const int c = tid & 63;
        const int r0 = (tid >> 6) * 8;
        float s[8];
        #pragma unroll
        for (int j = 0; j < 8; ++j) s[j] = b1s[c];
        #pragma unroll
        for (int k0 = 0; k0 < 64; k0 += 4) {
            const float w0 = W1s[k0 + 0][c], w1 = W1s[k0 + 1][c];
            const float w2 = W1s[k0 + 2][c], w3 = W1s[k0 + 3][c];
            #pragma unroll
            for (int j = 0; j < 8; ++j) {
                f32x4 hv = *(const f32x4*)&hs[r0 + j][k0];
                s[j] = fmaf(hv[0], w0, s[j]);
                s[j] = fmaf(hv[1], w1, s[j]);
                s[j] = fmaf(hv[2], w2, s[j]);
                s[j] = fmaf(hv[3], w3, s[j]);
            }
        }
        #pragma unroll
        for (int j = 0; j < 8; ++j) Ts[r0 + j][c] = fmaxf(s[j], 0.0f);
    }
    __syncthreads();
    {
        const int c = tid & 127;
        const int r0 = (tid >> 7) * 16;
        float s[16];
        #pragma unroll
        for (int j = 0; j < 16; ++j) s[j] = b2s[c];
        #pragma unroll
        for (int k0 = 0; k0 < 64; k0 += 4) {
            const float w0 = W2s[k0 + 0][c], w1 = W2s[k0 + 1][c];
            const float w2 = W2s[k0 + 2][c], w3 = W2s[k0 + 3][c];
            #pragma unroll
            for (int j = 0; j < 16; ++j) {
                f32x4 tv = *(const f32x4*)&Ts[r0 + j][k0];
                s[j] = fmaf(tv[0], w0, s[j]);
                s[j] = fmaf(tv[1], w1, s[j]);
                s[j] = fmaf(tv[2], w2, s[j]);
                s[j] = fmaf(tv[3], w3, s[j]);
            }
        }
        #pragma unroll
        for (int j = 0; j < 16; ++j)
            Zf[(size_t)(row0 + r0 + j) * ZD + c] = (_Float16)s[j];
    }
}

// ---------------------------------------------------------------------------
// k3: 2080 upper tiles, XCD-swizzled, 128x128 per block, 4 waves,
// 4 blocks/CU (LDS ~34 KB, VGPR capped via launch_bounds(256,4)).
// Direct-global f16 MFMA fragment loads (Zf = 2 MiB, L2-resident).
// Register-direct epilogue: logits [i,j] scalar nt-stores + [j,i] f32x4
// nt-store per fragment (bitwise-symmetric L); v = sigmoid(gumbel+L) -> u8
// bytes straight into vT (col-major) and vTT (row-major) LDS; rs/cs LDS
// atomics. One final barrier, coalesced u32 flush of symmetric vfull,
// global atomicAdd of row sums.
// ---------------------------------------------------------------------------
__global__ __launch_bounds__(256, 4) void k3_main(
    const _Float16* __restrict__ Zf, const float* __restrict__ noise,
    float* __restrict__ logits, unsigned char* __restrict__ vfull,
    float* __restrict__ sums)
{
    int ti, tj;
    const int t = (blockIdx.x & 7) * (NUPPER / 8) + (blockIdx.x >> 3);  // XCD swizzle
    tile_decode(t, ti, tj);
    const bool diag = (ti == tj);

    __shared__ unsigned char vTT[128 * 132];   // [row][col] bytes, 16896 B
    __shared__ unsigned char vT[128 * 132];    // [col][row] bytes, 16896 B
    __shared__ float rs[128], cs[128];

    const int tid = threadIdx.x;
    const int lane = tid & 63;
    const int w = tid >> 6;
    const int wr = w >> 1, wc = w & 1;
    const int fr = lane & 15;
    const int kg = lane >> 4;
    const int i0 = ti * 128, j0 = tj * 128;

    if (tid < 128) { rs[tid] = 0.0f; cs[tid] = 0.0f; }

    const _Float16* Ap = Zf + (size_t)(i0 + wr * 64) * ZD;
    const _Float16* Bp = Zf + (size_t)(j0 + wc * 64) * ZD;

    f32x4 acc[4][4];
    #pragma unroll
    for (int mf = 0; mf < 4; ++mf)
        #pragma unroll
        for (int nf = 0; nf < 4; ++nf)
            acc[mf][nf] = (f32x4)0.0f;

    #pragma unroll
    for (int kc = 0; kc < 4; ++kc) {
        const int ko = kc * 32 + kg * 8;
        f16x8 a[4], b[4];
        #pragma unroll
        for (int mf = 0; mf < 4; ++mf) {
            size_t off = (size_t)(mf * 16 + fr) * ZD + ko;
            a[mf] = *(const f16x8*)(Ap + off);
            b[mf] = *(const f16x8*)(Bp + off);
        }
        #pragma unroll
        for (int mf = 0; mf < 4; ++mf)
            #pragma unroll
            for (int nf = 0; nf < 4; ++nf)
                acc[mf][nf] = __builtin_amdgcn_mfma_f32_16x16x32_f16(a[mf], b[nf], acc[mf][nf], 0, 0, 0);
    }
    __syncthreads();   // rs/cs init visible; vT/vTT free to write

    // ---- register-direct epilogue ----
    float cacc[4] = {0.f, 0.f, 0.f, 0.f};
    #pragma unroll
    for (int mf = 0; mf < 4; ++mf) {
        const int Rl = wr * 64 + mf * 16 + (lane >> 4) * 4;   // local rows Rl..Rl+3
        f32x4 rsum4 = (f32x4)0.0f;
        #pragma unroll
        for (int nf = 0; nf < 4; ++nf) {
            const int Cl = wc * 64 + nf * 16 + (lane & 15);   // local col
            const f32x4 Lv = acc[mf][nf];
            const size_t gi = (size_t)(i0 + Rl) * N + (j0 + Cl);
            #pragma unroll
            for (int k = 0; k < 4; ++k)
                __builtin_nontemporal_store(Lv[k], &logits[gi + (size_t)k * N]);
            __builtin_nontemporal_store(Lv, (f32x4*)&logits[(size_t)(j0 + Cl) * N + (i0 + Rl)]);
            unsigned q = 0;
            #pragma unroll
            for (int k = 0; k < 4; ++k) {
                float u = __builtin_nontemporal_load(&noise[gi + (size_t)k * N]);
                float eps = fmaf(-0.9998f, u, 0.9999f);   // eps in [1e-4, 1-1e-4]
                float om  = fmaf( 0.9998f, u, 0.0001f);   // 1 - eps
                float gate = __logf(eps) - __logf(om) + Lv[k];
                float v = 1.0f / (1.0f + __expf(-gate));
                if (diag && (Rl + k) >= Cl) v = 0.0f;     // strict upper only
                q |= ((unsigned)(int)rintf(v * 255.0f)) << (8 * k);
                rsum4[k] += v;
                cacc[nf] += v;
            }
            *(unsigned*)&vT[Cl * 132 + Rl] = q;
            #pragma unroll
            for (int k = 0; k < 4; ++k)
                vTT[(Rl + k) * 132 + Cl] = (unsigned char)((q >> (8 * k)) & 255);
        }
        #pragma unroll
        for (int k = 0; k < 4; ++k)
            atomicAdd(&rs[Rl + k], rsum4[k]);
    }
    #pragma unroll
    for (int nf = 0; nf < 4; ++nf)
        atomicAdd(&cs[wc * 64 + nf * 16 + (lane & 15)], cacc[nf]);

    __syncthreads();   // vT/vTT + rs/cs complete

    // ---- coalesced vfull flush + global sums ----
    if (!diag) {
        #pragma unroll
        for (int it = 0; it < 16; ++it) {
            const int idx = tid + it * 256;
            const int r = idx >> 5;
            const int c4 = (idx & 31) * 4;
            const unsigned q = *(const unsigned*)&vTT[r * 132 + c4];
            __builtin_nontemporal_store(q, (unsigned*)&vfull[(size_t)(i0 + r) * N + j0 + c4]);
        }
        #pragma unroll
        for (int it = 0; it < 16; ++it) {
            const int idx = tid + it * 256;
            const int c = idx >> 5;
            const int r4 = (idx & 31) * 4;
            const unsigned q = *(const unsigned*)&vT[c * 132 + r4];
            __builtin_nontemporal_store(q, (unsigned*)&vfull[(size_t)(j0 + c) * N + i0 + r4]);
        }
        if (tid < 128) {
            atomicAdd(&sums[i0 + tid], rs[tid]);
            atomicAdd(&sums[j0 + tid], cs[tid]);
        }
    } else {
        #pragma unroll
        for (int it = 0; it < 16; ++it) {
            const int idx = tid + it * 256;
            const int r = idx >> 5;
            const int c4 = (idx & 31) * 4;
            unsigned q = 0;
            #pragma unroll
            for (int e = 0; e < 4; ++e) {
                const int c = c4 + e;
                unsigned char b = (unsigned char)(vTT[r * 132 + c] | vTT[c * 132 + r]);
                q |= ((unsigned)b) << (8 * e);
            }
            __builtin_nontemporal_store(q, (unsigned*)&vfull[(size_t)(i0 + r) * N + j0 + c4]);
        }
        if (tid < 128)
            atomicAdd(&sums[i0 + tid], rs[tid] + cs[tid]);
    }
}

// ---------------------------------------------------------------------------
// k4: d = rsqrt(rowsum)
// ---------------------------------------------------------------------------
__global__ void k4_dvec(const float* __restrict__ sums, float* __restrict__ dvec)
{
    int i = blockIdx.x * 256 + threadIdx.x;
    if (i < N) dvec[i] = rsqrtf(sums[i]);
}

// ---------------------------------------------------------------------------
// k5: flat streaming normalize (u32 read -> f32x4 write, both coalesced).
// ---------------------------------------------------------------------------
__global__ __launch_bounds__(256) void k5_norm(
    const unsigned char* __restrict__ vfull, float* __restrict__ adj,
    const float* __restrict__ dvec)
{
    const unsigned CHUNKS_PER_ROW = N / 4;               // 2048
    const unsigned stride = gridDim.x * 256;
    const float inv255 = 1.0f / 255.0f;

    for (unsigned idx = blockIdx.x * 256 + threadIdx.x; idx < (unsigned)(N / 4) * N;
         idx += stride) {
        const unsigned row = idx / CHUNKS_PER_ROW;
        const unsigned col4 = (idx % CHUNKS_PER_ROW) * 4;
        const unsigned q = __builtin_nontemporal_load((const unsigned*)&vfull[(size_t)idx * 4]);
        const float sdi = dvec[row] * inv255;
        const f32x4 d4 = *(const f32x4*)&dvec[col4];
        f32x4 o;
        o[0] = (float)(q & 255)         * sdi * d4[0];
        o[1] = (float)((q >> 8) & 255)  * sdi * d4[1];
        o[2] = (float)((q >> 16) & 255) * sdi * d4[2];
        o[3] = (float)(q >> 24)         * sdi * d4[3];
        if (row - col4 < 4u) {
            const float di = dvec[row];
            o[row - col4] = di * di;
        }
        __builtin_nontemporal_store(o, (f32x4*)&adj[(size_t)idx * 4]);
    }
}

// ---------------------------------------------------------------------------
extern "C" void kernel_launch(void* const* d_in, const int* in_sizes, int n_in,
                              void* d_out, int out_size, void* d_ws, size_t ws_size,
                              hipStream_t stream)
{
    const float* h     = (const float*)d_in[0];
    const float* W1    = (const float*)d_in[1];
    const float* b1    = (const float*)d_in[2];
    const float* W2    = (const float*)d_in[3];
    const float* b2    = (const float*)d_in[4];
    const float* noise = (const float*)d_in[5];

    float* adj    = (float*)d_out;                 // output 0: adj_norm [N,N]
    float* logits = adj + (size_t)N * N;           // output 1: adj_logits [N,N]

    _Float16* Zf         = (_Float16*)d_ws;                        // 2 MiB
    unsigned char* vfull = (unsigned char*)(Zf + (size_t)N * ZD);  // [N,N] u8 = 64 MiB
    float* sums          = (float*)(vfull + (size_t)N * N);        // [N]
    float* dvec          = sums + N;                               // [N]

    k1_mlp<<<256, 256, 0, stream>>>(h, W1, b1, W2, b2, Zf, sums);
    k3_main<<<NUPPER, 256, 0, stream>>>(Zf, noise, logits, vfull, sums);
    k4_dvec<<<32, 256, 0, stream>>>(sums, dvec);
    k5_norm<<<4096, 256, 0, stream>>>(vfull, adj, dvec);
}

// Round 13
// 275.068 us; speedup vs baseline: 1.1656x; 1.1656x over previous
//
#include <hip/hip_runtime.h>
#include <hip/hip_bf16.h>
#include <math.h>

#define N 8192
#define ZD 128
#define NTILE 64            // N / 128
#define NUPPER 2080         // NTILE*(NTILE+1)/2  (= 8 * 260)

typedef __attribute__((ext_vector_type(8))) _Float16 f16x8;
typedef __attribute__((ext_vector_type(4))) float f32x4;

__device__ __forceinline__ int tri_cum(int ti) {   // tiles before row ti
    return (ti * (2 * NTILE + 1 - ti)) / 2;
}

__device__ __forceinline__ void tile_decode(int t, int& ti, int& tj) {
    int est = (int)((129.0f - sqrtf(16641.0f - 8.0f * (float)t)) * 0.5f);
    if (est < 0) est = 0;
    while (tri_cum(est) > t) --est;
    while (tri_cum(est + 1) <= t) ++est;
    ti = est;
    tj = est + (t - tri_cum(est));
}

// ---------------------------------------------------------------------------
// k1: Z = relu(h @ W1 + b1) @ W2 + b2 (fp32 math), stored as f16.
// Also initializes sums[i] = 1.0 (fill_diagonal contribution).
// ---------------------------------------------------------------------------
__global__ __launch_bounds__(256) void k1_mlp(
    const float* __restrict__ h, const float* __restrict__ W1,
    const float* __restrict__ b1, const float* __restrict__ W2,
    const float* __restrict__ b2, _Float16* __restrict__ Zf,
    float* __restrict__ sums)
{
    __shared__ float W1s[64][65];
    __shared__ float W2s[64][129];
    __shared__ float hs[32][68];
    __shared__ float Ts[32][68];
    __shared__ float b1s[64];
    __shared__ float b2s[128];
    const int tid = threadIdx.x;
    const int row0 = blockIdx.x * 32;

    if (tid < 32) sums[row0 + tid] = 1.0f;

    for (int e = tid; e < 64 * 64; e += 256) W1s[e >> 6][e & 63] = W1[e];
    for (int e = tid; e < 64 * 128; e += 256) W2s[e >> 7][e & 127] = W2[e];
    for (int e = tid; e < 32 * 64; e += 256) hs[e >> 6][e & 63] = h[(size_t)row0 * 64 + e];
    if (tid < 64) b1s[tid] = b1[tid];
    if (tid < 128) b2s[tid] = b2[tid];
    __syncthreads();

    {
        const int c = tid & 63;
        const int r0 = (tid >> 6) * 8;
        float s[8];
        #pragma unroll
        for (int j = 0; j < 8; ++j) s[j] = b1s[c];
        #pragma unroll
        for (int k0 = 0; k0 < 64; k0 += 4) {
            const float w0 = W1s[k0 + 0][c], w1 = W1s[k0 + 1][c];
            const float w2 = W1s[k0 + 2][c], w3 = W1s[k0 + 3][c];
            #pragma unroll
            for (int j = 0; j < 8; ++j) {
                f32x4 hv = *(const f32x4*)&hs[r0 + j][k0];
                s[j] = fmaf(hv[0], w0, s[j]);
                s[j] = fmaf(hv[1], w1, s[j]);
                s[j] = fmaf(hv[2], w2, s[j]);
                s[j] = fmaf(hv[3], w3, s[j]);
            }
        }
        #pragma unroll
        for (int j = 0; j < 8; ++j) Ts[r0 + j][c] = fmaxf(s[j], 0.0f);
    }
    __syncthreads();
    {
        const int c = tid & 127;
        const int r0 = (tid >> 7) * 16;
        float s[16];
        #pragma unroll
        for (int j = 0; j < 16; ++j) s[j] = b2s[c];
        #pragma unroll
        for (int k0 = 0; k0 < 64; k0 += 4) {
            const float w0 = W2s[k0 + 0][c], w1 = W2s[k0 + 1][c];
            const float w2 = W2s[k0 + 2][c], w3 = W2s[k0 + 3][c];
            #pragma unroll
            for (int j = 0; j < 16; ++j) {
                f32x4 tv = *(const f32x4*)&Ts[r0 + j][k0];
                s[j] = fmaf(tv[0], w0, s[j]);
                s[j] = fmaf(tv[1], w1, s[j]);
                s[j] = fmaf(tv[2], w2, s[j]);
                s[j] = fmaf(tv[3], w3, s[j]);
            }
        }
        #pragma unroll
        for (int j = 0; j < 16; ++j)
            Zf[(size_t)(row0 + r0 + j) * ZD + c] = (_Float16)s[j];
    }
}

// ---------------------------------------------------------------------------
// k3: 4160 blocks = 2080 upper tiles x 2 column-halves (XCD-swizzled on the
// tile index). Each block: 128 rows x 64 cols, 4 waves of 64x32 -> acc is
// only 8 f32x4 = 32 VGPRs -> launch_bounds(256,5) = 20 waves/CU, no spill.
// Direct-global f16 MFMA fragment loads (Zf 2 MiB, L2-resident).
// Register-direct epilogue: logits [i,j] scalar nt-stores + [j,i] f32x4
// nt-scatter (bitwise-symmetric L); v = sigmoid(gumbel+L) -> u8 into vTT LDS;
// rs/cs LDS atomics; one barrier; coalesced u32 flush into the COMPACT
// per-tile vtile (k5 mirrors it); global sums atomics.
// ---------------------------------------------------------------------------
__global__ __launch_bounds__(256, 5) void k3_main(
    const _Float16* __restrict__ Zf, const float* __restrict__ noise,
    float* __restrict__ logits, unsigned char* __restrict__ vws,
    float* __restrict__ sums)
{
    const int tt = blockIdx.x >> 1;
    const int t = (tt & 7) * (NUPPER / 8) + (tt >> 3);   // XCD swizzle (2080 = 8*260)
    const int h = blockIdx.x & 1;                        // column half of the tile
    int ti, tj;
    tile_decode(t, ti, tj);
    const bool diag = (ti == tj);
    const int i0 = ti * 128;
    const int j0 = tj * 128 + h * 64;

    __shared__ unsigned char vTT[128 * 68];   // [row][col(64)+4 pad]
    __shared__ float rs[128], cs[64];

    const int tid = threadIdx.x;
    const int lane = tid & 63;
    const int w = tid >> 6;
    const int wr = w >> 1, wcc = w & 1;       // wave: 2 row-halves x 2 col-32s
    const int fr = lane & 15;
    const int kg = lane >> 4;

    if (tid < 128) rs[tid] = 0.0f;
    if (tid < 64) cs[tid] = 0.0f;

    const _Float16* Ap = Zf + (size_t)(i0 + wr * 64) * ZD;
    const _Float16* Bp = Zf + (size_t)(j0 + wcc * 32) * ZD;

    f32x4 acc[4][2];
    #pragma unroll
    for (int mf = 0; mf < 4; ++mf)
        #pragma unroll
        for (int nf = 0; nf < 2; ++nf)
            acc[mf][nf] = (f32x4)0.0f;

    #pragma unroll
    for (int kc = 0; kc < 4; ++kc) {
        const int ko = kc * 32 + kg * 8;
        f16x8 a[4], b[2];
        #pragma unroll
        for (int mf = 0; mf < 4; ++mf)
            a[mf] = *(const f16x8*)(Ap + (size_t)(mf * 16 + fr) * ZD + ko);
        #pragma unroll
        for (int nf = 0; nf < 2; ++nf)
            b[nf] = *(const f16x8*)(Bp + (size_t)(nf * 16 + fr) * ZD + ko);
        #pragma unroll
        for (int mf = 0; mf < 4; ++mf)
            #pragma unroll
            for (int nf = 0; nf < 2; ++nf)
                acc[mf][nf] = __builtin_amdgcn_mfma_f32_16x16x32_f16(a[mf], b[nf], acc[mf][nf], 0, 0, 0);
    }
    __syncthreads();   // rs/cs init visible before epilogue atomics

    // ---- register-direct epilogue ----
    float cacc[2] = {0.f, 0.f};
    #pragma unroll
    for (int mf = 0; mf < 4; ++mf) {
        const int Rl = wr * 64 + mf * 16 + (lane >> 4) * 4;   // local rows Rl..Rl+3
        f32x4 rsum4 = (f32x4)0.0f;
        #pragma unroll
        for (int nf = 0; nf < 2; ++nf) {
            const int Cl = wcc * 32 + nf * 16 + (lane & 15);  // local col (0..63)
            const f32x4 Lv = acc[mf][nf];
            const size_t gi = (size_t)(i0 + Rl) * N + (j0 + Cl);
            #pragma unroll
            for (int k = 0; k < 4; ++k)
                __builtin_nontemporal_store(Lv[k], &logits[gi + (size_t)k * N]);
            __builtin_nontemporal_store(Lv, (f32x4*)&logits[(size_t)(j0 + Cl) * N + (i0 + Rl)]);
            unsigned q = 0;
            #pragma unroll
            for (int k = 0; k < 4; ++k) {
                float u = __builtin_nontemporal_load(&noise[gi + (size_t)k * N]);
                float eps = fmaf(-0.9998f, u, 0.9999f);   // eps in [1e-4, 1-1e-4]
                float om  = fmaf( 0.9998f, u, 0.0001f);   // 1 - eps
                float gate = __logf(eps) - __logf(om) + Lv[k];
                float v = 1.0f / (1.0f + __expf(-gate));
                if (diag && (i0 + Rl + k) >= (j0 + Cl)) v = 0.0f;  // strict upper
                q |= ((unsigned)(int)rintf(v * 255.0f)) << (8 * k);
                rsum4[k] += v;
                cacc[nf] += v;
            }
            #pragma unroll
            for (int k = 0; k < 4; ++k)
                vTT[(Rl + k) * 68 + Cl] = (unsigned char)((q >> (8 * k)) & 255);
        }
        #pragma unroll
        for (int k = 0; k < 4; ++k)
            atomicAdd(&rs[Rl + k], rsum4[k]);
    }
    #pragma unroll
    for (int nf = 0; nf < 2; ++nf)
        atomicAdd(&cs[wcc * 32 + nf * 16 + (lane & 15)], cacc[nf]);

    __syncthreads();

    // ---- coalesced compact vtile flush (this tile's 64-col half) ----
    unsigned char* __restrict__ vtile = vws + (size_t)t * (128 * 128);
    #pragma unroll
    for (int it = 0; it < 8; ++it) {
        const int idx = tid + it * 256;       // 0..2047
        const int r = idx >> 4;               // 0..127
        const int c4 = (idx & 15) * 4;        // 0..60
        const unsigned q = *(const unsigned*)&vTT[r * 68 + c4];
        __builtin_nontemporal_store(q, (unsigned*)&vtile[r * 128 + h * 64 + c4]);
    }

    // ---- global row/col sums ----
    if (tid < 128) atomicAdd(&sums[i0 + tid], rs[tid]);
    if (tid < 64)  atomicAdd(&sums[j0 + tid], cs[tid]);
}

// ---------------------------------------------------------------------------
// k5: adj[i,j] = v_u8/255 * d_i * d_j (compact vtile), mirror to [j,i],
// diagonal = d_i^2. d = rsqrt(sums) per block (sums L2-resident).
// T is [col][row] 68-stride for 16B-aligned vectorized mirror stores.
// ---------------------------------------------------------------------------
__global__ __launch_bounds__(256, 4) void k5_norm(
    const unsigned char* __restrict__ vws, float* __restrict__ adj,
    const float* __restrict__ sums)
{
    int ti, tj;
    tile_decode(blockIdx.x, ti, tj);
    const bool diag = (ti == tj);
    __shared__ float T[128][68];
    __shared__ float drow[128], dcol[128];
    const int tid = threadIdx.x;
    const int i0 = ti * 128, j0 = tj * 128;

    const unsigned char* __restrict__ vtile = vws + (size_t)blockIdx.x * (128 * 128);

    if (tid < 128) drow[tid] = rsqrtf(sums[i0 + tid]);
    else dcol[tid - 128] = rsqrtf(sums[j0 + tid - 128]);
    __syncthreads();

    const float inv255 = 1.0f / 255.0f;
    #pragma unroll 4
    for (int it = 0; it < 16; ++it) {
        int w = tid + it * 256;
        int m = w >> 5;
        int n4 = (w & 31) << 2;
        unsigned q = __builtin_nontemporal_load((const unsigned*)&vtile[m * 128 + n4]);
        float dm = drow[m];
        f32x4 o;
        o[0] = (float)(q & 255)         * inv255 * dm * dcol[n4 + 0];
        o[1] = (float)((q >> 8) & 255)  * inv255 * dm * dcol[n4 + 1];
        o[2] = (float)((q >> 16) & 255) * inv255 * dm * dcol[n4 + 2];
        o[3] = (float)(q >> 24)         * inv255 * dm * dcol[n4 + 3];
        __builtin_nontemporal_store(o, (f32x4*)&adj[(size_t)(i0 + m) * N + j0 + n4]);
        T[n4 + 0][m] = o[0]; T[n4 + 1][m] = o[1];
        T[n4 + 2][m] = o[2]; T[n4 + 3][m] = o[3];
    }
    __syncthreads();
    // mirror: adj[j0+c][i0+m4..m4+3] = T[c][m4..m4+3] (contiguous, 16B aligned)
    #pragma unroll 4
    for (int it = 0; it < 16; ++it) {
        int w = tid + it * 256;
        int c = w >> 5;
        int m4 = (w & 31) << 2;
        f32x4 o = *(const f32x4*)&T[c][m4];
        if (!diag) {
            __builtin_nontemporal_store(o, (f32x4*)&adj[(size_t)(j0 + c) * N + i0 + m4]);
        } else {
            #pragma unroll
            for (int e = 0; e < 4; ++e)
                if (m4 + e < c)
                    adj[(size_t)(j0 + c) * N + i0 + m4 + e] = o[e];
        }
    }
    if (diag && tid < 128) {
        float dm = drow[tid];
        adj[(size_t)(i0 + tid) * N + i0 + tid] = dm * dm;
    }
}

// ---------------------------------------------------------------------------
extern "C" void kernel_launch(void* const* d_in, const int* in_sizes, int n_in,
                              void* d_out, int out_size, void* d_ws, size_t ws_size,
                              hipStream_t stream)
{
    const float* h     = (const float*)d_in[0];
    const float* W1    = (const float*)d_in[1];
    const float* b1    = (const float*)d_in[2];
    const float* W2    = (const float*)d_in[3];
    const float* b2    = (const float*)d_in[4];
    const float* noise = (const float*)d_in[5];

    float* adj    = (float*)d_out;                 // output 0: adj_norm [N,N]
    float* logits = adj + (size_t)N * N;           // output 1: adj_logits [N,N]

    _Float16* Zf       = (_Float16*)d_ws;                      // 2 MiB
    unsigned char* vws = (unsigned char*)(Zf + (size_t)N * ZD);// 2080*16384 u8 = 34 MiB
    float* sums        = (float*)(vws + (size_t)NUPPER * 128 * 128); // [N]

    k1_mlp<<<256, 256, 0, stream>>>(h, W1, b1, W2, b2, Zf, sums);
    k3_main<<<NUPPER * 2, 256, 0, stream>>>(Zf, noise, logits, vws, sums);
    k5_norm<<<NUPPER, 256, 0, stream>>>(vws, adj, sums);
}

// Round 14
// 221.712 us; speedup vs baseline: 1.4461x; 1.2407x over previous
//
#include <hip/hip_runtime.h>
#include <hip/hip_bf16.h>
#include <math.h>

#define N 8192
#define ZD 128
#define NTILE 64            // N / 128
#define NUPPER 2080         // NTILE*(NTILE+1)/2 (= 8 * 260)

typedef __attribute__((ext_vector_type(8))) _Float16 f16x8;
typedef __attribute__((ext_vector_type(4))) float f32x4;

__device__ __forceinline__ int tri_cum(int ti) {   // tiles before row ti
    return (ti * (2 * NTILE + 1 - ti)) / 2;        // ti*(129-ti)/2
}

__device__ __forceinline__ void tile_decode(int t, int& ti, int& tj) {
    int est = (int)((129.0f - sqrtf(16641.0f - 8.0f * (float)t)) * 0.5f);
    if (est < 0) est = 0;
    while (tri_cum(est) > t) --est;
    while (tri_cum(est + 1) <= t) ++est;
    ti = est;
    tj = est + (t - tri_cum(est));
}

// ---------------------------------------------------------------------------
// k1: Z = relu(h @ W1 + b1) @ W2 + b2 (fp32 math), stored as f16.
// Also initializes sums[i] = 1.0 (the fill_diagonal(1) contribution).
// ---------------------------------------------------------------------------
__global__ __launch_bounds__(256) void k1_mlp(
    const float* __restrict__ h, const float* __restrict__ W1,
    const float* __restrict__ b1, const float* __restrict__ W2,
    const float* __restrict__ b2, _Float16* __restrict__ Zf,
    float* __restrict__ sums)
{
    __shared__ float W1s[64][65];
    __shared__ float W2s[64][129];
    __shared__ float hs[32][68];
    __shared__ float Ts[32][68];
    __shared__ float b1s[64];
    __shared__ float b2s[128];
    const int tid = threadIdx.x;
    const int row0 = blockIdx.x * 32;

    if (tid < 32) sums[row0 + tid] = 1.0f;

    for (int e = tid; e < 64 * 64; e += 256) W1s[e >> 6][e & 63] = W1[e];
    for (int e = tid; e < 64 * 128; e += 256) W2s[e >> 7][e & 127] = W2[e];
    for (int e = tid; e < 32 * 64; e += 256) hs[e >> 6][e & 63] = h[(size_t)row0 * 64 + e];
    if (tid < 64) b1s[tid] = b1[tid];
    if (tid < 128) b2s[tid] = b2[tid];
    __syncthreads();

    // layer 1: 32x64 outputs, 8 rows per thread, shared weight broadcast
    {
        const int c = tid & 63;
        const int r0 = (tid >> 6) * 8;
        float s[8];
        #pragma unroll
        for (int j = 0; j < 8; ++j) s[j] = b1s[c];
        #pragma unroll
        for (int k0 = 0; k0 < 64; k0 += 4) {
            const float w0 = W1s[k0 + 0][c], w1 = W1s[k0 + 1][c];
            const float w2 = W1s[k0 + 2][c], w3 = W1s[k0 + 3][c];
            #pragma unroll
            for (int j = 0; j < 8; ++j) {
                f32x4 hv = *(const f32x4*)&hs[r0 + j][k0];
                s[j] = fmaf(hv[0], w0, s[j]);
                s[j] = fmaf(hv[1], w1, s[j]);
                s[j] = fmaf(hv[2], w2, s[j]);
                s[j] = fmaf(hv[3], w3, s[j]);
            }
        }
        #pragma unroll
        for (int j = 0; j < 8; ++j) Ts[r0 + j][c] = fmaxf(s[j], 0.0f);
    }
    __syncthreads();

    // layer 2: 32x128 outputs, 16 rows per thread
    {
        const int c = tid & 127;
        const int r0 = (tid >> 7) * 16;
        float s[16];
        #pragma unroll
        for (int j = 0; j < 16; ++j) s[j] = b2s[c];
        #pragma unroll
        for (int k0 = 0; k0 < 64; k0 += 4) {
            const float w0 = W2s[k0 + 0][c], w1 = W2s[k0 + 1][c];
            const float w2 = W2s[k0 + 2][c], w3 = W2s[k0 + 3][c];
            #pragma unroll
            for (int j = 0; j < 16; ++j) {
                f32x4 tv = *(const f32x4*)&Ts[r0 + j][k0];
                s[j] = fmaf(tv[0], w0, s[j]);
                s[j] = fmaf(tv[1], w1, s[j]);
                s[j] = fmaf(tv[2], w2, s[j]);
                s[j] = fmaf(tv[3], w3, s[j]);
            }
        }
        #pragma unroll
        for (int j = 0; j < 16; ++j)
            Zf[(size_t)(row0 + r0 + j) * ZD + c] = (_Float16)s[j];
    }
}

// ---------------------------------------------------------------------------
// k3: 2080 upper tiles (1-D grid, bijective XCD swizzle), 128x128 per block,
// 4 waves, 3 blocks/CU. Single-pass f16 MFMA GEMM, operands direct from L2.
// Epilogue: LDS-staged in two 64-col halves -> coalesced f32x4 nt-writes of
// logits [i,j], transposed [j,i], v = sigmoid(gumbel+L) via the 2-transcen-
// dental form  v = eps / (eps + (1-eps)*exp(-L)), quantized to u8 into the
// compact per-tile vtile buffer; row/col sums (fp32, pre-quantization).
// ---------------------------------------------------------------------------
__global__ __launch_bounds__(256, 3) void k3_main(
    const _Float16* __restrict__ Zf, const float* __restrict__ noise,
    float* __restrict__ logits, unsigned char* __restrict__ vws,
    float* __restrict__ sums)
{
    int ti, tj;
    const int t = (blockIdx.x & 7) * (NUPPER / 8) + (blockIdx.x >> 3);  // XCD swizzle
    tile_decode(t, ti, tj);
    const bool diag = (ti == tj);

    __shared__ float T[128][65];
    __shared__ float rs[128], cs[128];

    const int tid = threadIdx.x;
    const int lane = tid & 63;
    const int w = tid >> 6;
    const int wr = w >> 1, wc = w & 1;
    const int fr = lane & 15;     // fragment row (m/n within 16)
    const int kg = lane >> 4;     // k-group 0..3
    const int i0 = ti * 128, j0 = tj * 128;

    unsigned char* __restrict__ vtile = vws + (size_t)t * (128 * 128);

    if (tid < 128) { rs[tid] = 0.0f; cs[tid] = 0.0f; }

    const _Float16* Ap = Zf + (size_t)(i0 + wr * 64) * ZD;
    const _Float16* Bp = Zf + (size_t)(j0 + wc * 64) * ZD;

    f32x4 acc[4][4];
    #pragma unroll
    for (int mf = 0; mf < 4; ++mf)
        #pragma unroll
        for (int nf = 0; nf < 4; ++nf)
            acc[mf][nf] = (f32x4)0.0f;

    #pragma unroll
    for (int kc = 0; kc < 4; ++kc) {
        const int ko = kc * 32 + kg * 8;
        f16x8 a[4], b[4];
        #pragma unroll
        for (int mf = 0; mf < 4; ++mf) {
            size_t off = (size_t)(mf * 16 + fr) * ZD + ko;
            a[mf] = *(const f16x8*)(Ap + off);
            b[mf] = *(const f16x8*)(Bp + off);
        }
        #pragma unroll
        for (int mf = 0; mf < 4; ++mf)
            #pragma unroll
            for (int nf = 0; nf < 4; ++nf)
                acc[mf][nf] = __builtin_amdgcn_mfma_f32_16x16x32_f16(a[mf], b[nf], acc[mf][nf], 0, 0, 0);
    }

    // ---- epilogue in two 64-column halves ----
    const int c4 = (tid & 15) * 4;        // local col group within half
    const int rbase = tid >> 4;           // 0..15

    #pragma unroll
    for (int half = 0; half < 2; ++half) {
        __syncthreads();   // previous half's readers done / rs,cs init visible
        if (wc == half) {
            #pragma unroll
            for (int mf = 0; mf < 4; ++mf)
                #pragma unroll
                for (int nf = 0; nf < 4; ++nf)
                    #pragma unroll
                    for (int r = 0; r < 4; ++r)
                        T[wr * 64 + mf * 16 + (lane >> 4) * 4 + r][nf * 16 + fr] = acc[mf][nf][r];
        }
        __syncthreads();

        f32x4 csum = (f32x4)0.0f;
        #pragma unroll
        for (int it = 0; it < 8; ++it) {
            const int r = rbase + it * 16;
            f32x4 L4 = *(const f32x4*)&T[r][c4];
            const size_t g = (size_t)(i0 + r) * N + j0 + half * 64 + c4;
            __builtin_nontemporal_store(L4, (f32x4*)&logits[g]);
            f32x4 u4 = __builtin_nontemporal_load((const f32x4*)&noise[g]);
            float rsum = 0.0f;
            unsigned q = 0;
            #pragma unroll
            for (int e = 0; e < 4; ++e) {
                float u = u4[e];
                float eps = fmaf(-0.9998f, u, 0.9999f);   // eps in [1e-4, 1-1e-4]
                float om  = fmaf( 0.9998f, u, 0.0001f);   // 1 - eps
                // v = sigmoid(log(eps)-log(1-eps)+L) = eps/(eps + (1-eps)e^{-L})
                float ex = __expf(-L4[e]);
                float v = eps / fmaf(om, ex, eps);
                if (diag && r >= half * 64 + c4 + e) v = 0.0f;  // strict upper
                q |= ((unsigned)(int)rintf(v * 255.0f)) << (8 * e);
                rsum += v;
                csum[e] += v;
            }
            __builtin_nontemporal_store(q, (unsigned*)&vtile[r * 128 + half * 64 + c4]);
            atomicAdd(&rs[r], rsum);     // fire-and-forget, 16 lanes/row
        }
        #pragma unroll
        for (int e = 0; e < 4; ++e)
            atomicAdd(&cs[half * 64 + c4 + e], csum[e]);

        if (!diag) {
            #pragma unroll
            for (int it = 0; it < 8; ++it) {
                const int idx = tid + it * 256;     // 0..2047
                const int c = idx >> 5;             // 0..63
                const int m4 = (idx & 31) * 4;
                f32x4 o;
                o[0] = T[m4 + 0][c]; o[1] = T[m4 + 1][c];
                o[2] = T[m4 + 2][c]; o[3] = T[m4 + 3][c];
                __builtin_nontemporal_store(o, (f32x4*)&logits[(size_t)(j0 + half * 64 + c) * N + i0 + m4]);
            }
        }
    }

    __syncthreads();
    if (tid < 128) {
        if (diag) {
            atomicAdd(&sums[i0 + tid], rs[tid] + cs[tid]);
        } else {
            atomicAdd(&sums[i0 + tid], rs[tid]);
            atomicAdd(&sums[j0 + tid], cs[tid]);
        }
    }
}

// ---------------------------------------------------------------------------
// k5: adj[i,j] = v_u8/255 * d_i * d_j (from compact vtile), mirror to [j,i],
// diagonal = d_i^2. d = rsqrt(sums) recomputed per block (L2-resident sums).
// T is [col][row] with 68-stride for 16B-aligned vectorized mirror stores.
// ---------------------------------------------------------------------------
__global__ __launch_bounds__(256, 4) void k5_norm(
    const unsigned char* __restrict__ vws, float* __restrict__ adj,
    const float* __restrict__ sums)
{
    int ti, tj;
    const int t = (blockIdx.x & 7) * (NUPPER / 8) + (blockIdx.x >> 3);  // XCD swizzle
    tile_decode(t, ti, tj);
    const bool diag = (ti == tj);
    __shared__ float T[128][68];
    __shared__ float drow[128], dcol[128];
    const int tid = threadIdx.x;
    const int i0 = ti * 128, j0 = tj * 128;

    const unsigned char* __restrict__ vtile = vws + (size_t)t * (128 * 128);

    if (tid < 128) drow[tid] = rsqrtf(sums[i0 + tid]);
    else dcol[tid - 128] = rsqrtf(sums[j0 + tid - 128]);
    __syncthreads();

    const float inv255 = 1.0f / 255.0f;
    #pragma unroll 4
    for (int it = 0; it < 16; ++it) {
        int w = tid + it * 256;
        int m = w >> 5;
        int n4 = (w & 31) << 2;
        unsigned q = __builtin_nontemporal_load((const unsigned*)&vtile[m * 128 + n4]);
        float dm = drow[m];
        f32x4 o;
        o[0] = (float)(q & 255)         * inv255 * dm * dcol[n4 + 0];
        o[1] = (float)((q >> 8) & 255)  * inv255 * dm * dcol[n4 + 1];
        o[2] = (float)((q >> 16) & 255) * inv255 * dm * dcol[n4 + 2];
        o[3] = (float)(q >> 24)         * inv255 * dm * dcol[n4 + 3];
        __builtin_nontemporal_store(o, (f32x4*)&adj[(size_t)(i0 + m) * N + j0 + n4]);
        T[n4 + 0][m] = o[0]; T[n4 + 1][m] = o[1];
        T[n4 + 2][m] = o[2]; T[n4 + 3][m] = o[3];
    }
    __syncthreads();
    // mirror: adj[j0+c][i0+m4..m4+3] = T[c][m4..m4+3] (contiguous, 16B aligned)
    #pragma unroll 4
    for (int it = 0; it < 16; ++it) {
        int w = tid + it * 256;
        int c = w >> 5;
        int m4 = (w & 31) << 2;
        f32x4 o = *(const f32x4*)&T[c][m4];
        if (!diag) {
            __builtin_nontemporal_store(o, (f32x4*)&adj[(size_t)(j0 + c) * N + i0 + m4]);
        } else {
            #pragma unroll
            for (int e = 0; e < 4; ++e)
                if (m4 + e < c)
                    adj[(size_t)(j0 + c) * N + i0 + m4 + e] = o[e];
        }
    }
    if (diag && tid < 128) {
        float dm = drow[tid];
        adj[(size_t)(i0 + tid) * N + i0 + tid] = dm * dm;
    }
}

// ---------------------------------------------------------------------------
extern "C" void kernel_launch(void* const* d_in, const int* in_sizes, int n_in,
                              void* d_out, int out_size, void* d_ws, size_t ws_size,
                              hipStream_t stream)
{
    const float* h     = (const float*)d_in[0];
    const float* W1    = (const float*)d_in[1];
    const float* b1    = (const float*)d_in[2];
    const float* W2    = (const float*)d_in[3];
    const float* b2    = (const float*)d_in[4];
    const float* noise = (const float*)d_in[5];

    float* adj    = (float*)d_out;                 // output 0: adj_norm [N,N]
    float* logits = adj + (size_t)N * N;           // output 1: adj_logits [N,N]

    _Float16* Zf       = (_Float16*)d_ws;                      // 2 MiB
    unsigned char* vws = (unsigned char*)(Zf + (size_t)N * ZD);// 2080*16384 u8 = 34 MiB
    float* sums        = (float*)(vws + (size_t)NUPPER * 128 * 128); // [N]

    k1_mlp<<<256, 256, 0, stream>>>(h, W1, b1, W2, b2, Zf, sums);
    k3_main<<<NUPPER, 256, 0, stream>>>(Zf, noise, logits, vws, sums);
    k5_norm<<<NUPPER, 256, 0, stream>>>(vws, adj, sums);
}

// Round 15
// 213.665 us; speedup vs baseline: 1.5006x; 1.0377x over previous
//
#include <hip/hip_runtime.h>
#include <hip/hip_bf16.h>
#include <math.h>

#define N 8192
#define ZD 128
#define NTILE 64            // N / 128
#define NUPPER 2080         // NTILE*(NTILE+1)/2 (= 8 * 260)

typedef __attribute__((ext_vector_type(8))) _Float16 f16x8;
typedef __attribute__((ext_vector_type(4))) float f32x4;

__device__ __forceinline__ int tri_cum(int ti) {   // tiles before row ti
    return (ti * (2 * NTILE + 1 - ti)) / 2;        // ti*(129-ti)/2
}

__device__ __forceinline__ void tile_decode(int t, int& ti, int& tj) {
    int est = (int)((129.0f - sqrtf(16641.0f - 8.0f * (float)t)) * 0.5f);
    if (est < 0) est = 0;
    while (tri_cum(est) > t) --est;
    while (tri_cum(est + 1) <= t) ++est;
    ti = est;
    tj = est + (t - tri_cum(est));
}

// ---------------------------------------------------------------------------
// k1: Z = relu(h @ W1 + b1) @ W2 + b2 (fp32 math), stored as f16.
// Also initializes sums[i] = 1.0 (the fill_diagonal(1) contribution).
// ---------------------------------------------------------------------------
__global__ __launch_bounds__(256) void k1_mlp(
    const float* __restrict__ h, const float* __restrict__ W1,
    const float* __restrict__ b1, const float* __restrict__ W2,
    const float* __restrict__ b2, _Float16* __restrict__ Zf,
    float* __restrict__ sums)
{
    __shared__ float W1s[64][65];
    __shared__ float W2s[64][129];
    __shared__ float hs[32][68];
    __shared__ float Ts[32][68];
    __shared__ float b1s[64];
    __shared__ float b2s[128];
    const int tid = threadIdx.x;
    const int row0 = blockIdx.x * 32;

    if (tid < 32) sums[row0 + tid] = 1.0f;

    for (int e = tid; e < 64 * 64; e += 256) W1s[e >> 6][e & 63] = W1[e];
    for (int e = tid; e < 64 * 128; e += 256) W2s[e >> 7][e & 127] = W2[e];
    for (int e = tid; e < 32 * 64; e += 256) hs[e >> 6][e & 63] = h[(size_t)row0 * 64 + e];
    if (tid < 64) b1s[tid] = b1[tid];
    if (tid < 128) b2s[tid] = b2[tid];
    __syncthreads();

    // layer 1: 32x64 outputs, 8 rows per thread, shared weight broadcast
    {
        const int c = tid & 63;
        const int r0 = (tid >> 6) * 8;
        float s[8];
        #pragma unroll
        for (int j = 0; j < 8; ++j) s[j] = b1s[c];
        #pragma unroll
        for (int k0 = 0; k0 < 64; k0 += 4) {
            const float w0 = W1s[k0 + 0][c], w1 = W1s[k0 + 1][c];
            const float w2 = W1s[k0 + 2][c], w3 = W1s[k0 + 3][c];
            #pragma unroll
            for (int j = 0; j < 8; ++j) {
                f32x4 hv = *(const f32x4*)&hs[r0 + j][k0];
                s[j] = fmaf(hv[0], w0, s[j]);
                s[j] = fmaf(hv[1], w1, s[j]);
                s[j] = fmaf(hv[2], w2, s[j]);
                s[j] = fmaf(hv[3], w3, s[j]);
            }
        }
        #pragma unroll
        for (int j = 0; j < 8; ++j) Ts[r0 + j][c] = fmaxf(s[j], 0.0f);
    }
    __syncthreads();

    // layer 2: 32x128 outputs, 16 rows per thread
    {
        const int c = tid & 127;
        const int r0 = (tid >> 7) * 16;
        float s[16];
        #pragma unroll
        for (int j = 0; j < 16; ++j) s[j] = b2s[c];
        #pragma unroll
        for (int k0 = 0; k0 < 64; k0 += 4) {
            const float w0 = W2s[k0 + 0][c], w1 = W2s[k0 + 1][c];
            const float w2 = W2s[k0 + 2][c], w3 = W2s[k0 + 3][c];
            #pragma unroll
            for (int j = 0; j < 16; ++j) {
                f32x4 tv = *(const f32x4*)&Ts[r0 + j][k0];
                s[j] = fmaf(tv[0], w0, s[j]);
                s[j] = fmaf(tv[1], w1, s[j]);
                s[j] = fmaf(tv[2], w2, s[j]);
                s[j] = fmaf(tv[3], w3, s[j]);
            }
        }
        #pragma unroll
        for (int j = 0; j < 16; ++j)
            Zf[(size_t)(row0 + r0 + j) * ZD + c] = (_Float16)s[j];
    }
}

// ---------------------------------------------------------------------------
// k3: 2080 upper tiles (1-D grid, bijective XCD swizzle), 128x128 per block,
// 4 waves, 3 blocks/CU. Single-pass f16 MFMA GEMM, operands direct from L2.
// Epilogue: LDS-staged in two 64-col halves -> coalesced f32x4 nt-writes of
// logits [i,j], transposed [j,i]; v via v = eps/(eps+(1-eps)e^{-L}) (2
// transcendentals), u8-quantized into the compact per-tile vtile buffer.
// Row/col sums: NO ATOMICS in the hot path -- register accumulators, each
// (slot,owner) unique -> plain stores into rs2[128][16]/cs2[16][128], one
// barrier, 128-thread reduce, then global atomics.
// ---------------------------------------------------------------------------
__global__ __launch_bounds__(256, 3) void k3_main(
    const _Float16* __restrict__ Zf, const float* __restrict__ noise,
    float* __restrict__ logits, unsigned char* __restrict__ vws,
    float* __restrict__ sums)
{
    int ti, tj;
    const int t = (blockIdx.x & 7) * (NUPPER / 8) + (blockIdx.x >> 3);  // XCD swizzle
    tile_decode(t, ti, tj);
    const bool diag = (ti == tj);

    __shared__ float T[128][65];       // 33280 B
    __shared__ float rs2[128][16];     // 8192 B: [row][cid], owner-unique slots
    __shared__ float cs2[16][128];     // 8192 B: [rbase][col], owner-unique slots

    const int tid = threadIdx.x;
    const int lane = tid & 63;
    const int w = tid >> 6;
    const int wr = w >> 1, wc = w & 1;
    const int fr = lane & 15;     // fragment row (m/n within 16)
    const int kg = lane >> 4;     // k-group 0..3
    const int i0 = ti * 128, j0 = tj * 128;

    unsigned char* __restrict__ vtile = vws + (size_t)t * (128 * 128);

    const _Float16* Ap = Zf + (size_t)(i0 + wr * 64) * ZD;
    const _Float16* Bp = Zf + (size_t)(j0 + wc * 64) * ZD;

    f32x4 acc[4][4];
    #pragma unroll
    for (int mf = 0; mf < 4; ++mf)
        #pragma unroll
        for (int nf = 0; nf < 4; ++nf)
            acc[mf][nf] = (f32x4)0.0f;

    #pragma unroll
    for (int kc = 0; kc < 4; ++kc) {
        const int ko = kc * 32 + kg * 8;
        f16x8 a[4], b[4];
        #pragma unroll
        for (int mf = 0; mf < 4; ++mf) {
            size_t off = (size_t)(mf * 16 + fr) * ZD + ko;
            a[mf] = *(const f16x8*)(Ap + off);
            b[mf] = *(const f16x8*)(Bp + off);
        }
        #pragma unroll
        for (int mf = 0; mf < 4; ++mf)
            #pragma unroll
            for (int nf = 0; nf < 4; ++nf)
                acc[mf][nf] = __builtin_amdgcn_mfma_f32_16x16x32_f16(a[mf], b[nf], acc[mf][nf], 0, 0, 0);
    }

    // ---- epilogue in two 64-column halves ----
    const int cid = tid & 15;
    const int c4 = cid * 4;               // local col group within half
    const int rbase = tid >> 4;           // 0..15

    float rsacc[8];                       // per-thread row partials (both halves)
    #pragma unroll
    for (int it = 0; it < 8; ++it) rsacc[it] = 0.0f;

    #pragma unroll
    for (int half = 0; half < 2; ++half) {
        __syncthreads();   // previous half's T readers done
        if (wc == half) {
            #pragma unroll
            for (int mf = 0; mf < 4; ++mf)
                #pragma unroll
                for (int nf = 0; nf < 4; ++nf)
                    #pragma unroll
                    for (int r = 0; r < 4; ++r)
                        T[wr * 64 + mf * 16 + (lane >> 4) * 4 + r][nf * 16 + fr] = acc[mf][nf][r];
        }
        __syncthreads();

        f32x4 csum = (f32x4)0.0f;
        #pragma unroll
        for (int it = 0; it < 8; ++it) {
            const int r = rbase + it * 16;
            f32x4 L4 = *(const f32x4*)&T[r][c4];
            const size_t g = (size_t)(i0 + r) * N + j0 + half * 64 + c4;
            __builtin_nontemporal_store(L4, (f32x4*)&logits[g]);
            f32x4 u4 = __builtin_nontemporal_load((const f32x4*)&noise[g]);
            float rsum = 0.0f;
            unsigned q = 0;
            #pragma unroll
            for (int e = 0; e < 4; ++e) {
                float u = u4[e];
                float eps = fmaf(-0.9998f, u, 0.9999f);   // eps in [1e-4, 1-1e-4]
                float om  = fmaf( 0.9998f, u, 0.0001f);   // 1 - eps
                // v = sigmoid(log(eps)-log(1-eps)+L) = eps/(eps + (1-eps)e^{-L})
                float ex = __expf(-L4[e]);
                float v = eps / fmaf(om, ex, eps);
                if (diag && r >= half * 64 + c4 + e) v = 0.0f;  // strict upper
                q |= ((unsigned)(int)rintf(v * 255.0f)) << (8 * e);
                rsum += v;
                csum[e] += v;
            }
            __builtin_nontemporal_store(q, (unsigned*)&vtile[r * 128 + half * 64 + c4]);
            rsacc[it] += rsum;            // register accumulate, no LDS traffic
        }
        #pragma unroll
        for (int e = 0; e < 4; ++e)
            cs2[rbase][half * 64 + c4 + e] = csum[e];   // owner-unique, plain store

        if (!diag) {
            #pragma unroll
            for (int it = 0; it < 8; ++it) {
                const int idx = tid + it * 256;     // 0..2047
                const int c = idx >> 5;             // 0..63
                const int m4 = (idx & 31) * 4;
                f32x4 o;
                o[0] = T[m4 + 0][c]; o[1] = T[m4 + 1][c];
                o[2] = T[m4 + 2][c]; o[3] = T[m4 + 3][c];
                __builtin_nontemporal_store(o, (f32x4*)&logits[(size_t)(j0 + half * 64 + c) * N + i0 + m4]);
            }
        }
    }

    // row partials: each (row, cid) slot owned by exactly this thread
    #pragma unroll
    for (int it = 0; it < 8; ++it)
        rs2[rbase + it * 16][cid] = rsacc[it];

    __syncthreads();

    if (tid < 128) {
        // row sum: reduce rs2[tid][0..15]
        f32x4 a0 = *(const f32x4*)&rs2[tid][0];
        f32x4 a1 = *(const f32x4*)&rs2[tid][4];
        f32x4 a2 = *(const f32x4*)&rs2[tid][8];
        f32x4 a3 = *(const f32x4*)&rs2[tid][12];
        f32x4 s4 = a0 + a1 + a2 + a3;
        float rowsum = s4[0] + s4[1] + s4[2] + s4[3];
        // col sum: reduce cs2[0..15][tid]
        float colsum = 0.0f;
        #pragma unroll
        for (int k = 0; k < 16; ++k) colsum += cs2[k][tid];
        if (diag) {
            atomicAdd(&sums[i0 + tid], rowsum + colsum);
        } else {
            atomicAdd(&sums[i0 + tid], rowsum);
            atomicAdd(&sums[j0 + tid], colsum);
        }
    }
}

// ---------------------------------------------------------------------------
// k5: adj[i,j] = v_u8/255 * d_i * d_j (from compact vtile), mirror to [j,i],
// diagonal = d_i^2. d = rsqrt(sums) recomputed per block (L2-resident sums).
// T is [col][row] with 68-stride for 16B-aligned vectorized mirror stores.
// ---------------------------------------------------------------------------
__global__ __launch_bounds__(256, 4) void k5_norm(
    const unsigned char* __restrict__ vws, float* __restrict__ adj,
    const float* __restrict__ sums)
{
    int ti, tj;
    const int t = (blockIdx.x & 7) * (NUPPER / 8) + (blockIdx.x >> 3);  // XCD swizzle
    tile_decode(t, ti, tj);
    const bool diag = (ti == tj);
    __shared__ float T[128][68];
    __shared__ float drow[128], dcol[128];
    const int tid = threadIdx.x;
    const int i0 = ti * 128, j0 = tj * 128;

    const unsigned char* __restrict__ vtile = vws + (size_t)t * (128 * 128);

    if (tid < 128) drow[tid] = rsqrtf(sums[i0 + tid]);
    else dcol[tid - 128] = rsqrtf(sums[j0 + tid - 128]);
    __syncthreads();

    const float inv255 = 1.0f / 255.0f;
    #pragma unroll 4
    for (int it = 0; it < 16; ++it) {
        int w = tid + it * 256;
        int m = w >> 5;
        int n4 = (w & 31) << 2;
        unsigned q = __builtin_nontemporal_load((const unsigned*)&vtile[m * 128 + n4]);
        float dm = drow[m];
        f32x4 o;
        o[0] = (float)(q & 255)         * inv255 * dm * dcol[n4 + 0];
        o[1] = (float)((q >> 8) & 255)  * inv255 * dm * dcol[n4 + 1];
        o[2] = (float)((q >> 16) & 255) * inv255 * dm * dcol[n4 + 2];
        o[3] = (float)(q >> 24)         * inv255 * dm * dcol[n4 + 3];
        __builtin_nontemporal_store(o, (f32x4*)&adj[(size_t)(i0 + m) * N + j0 + n4]);
        T[n4 + 0][m] = o[0]; T[n4 + 1][m] = o[1];
        T[n4 + 2][m] = o[2]; T[n4 + 3][m] = o[3];
    }
    __syncthreads();
    // mirror: adj[j0+c][i0+m4..m4+3] = T[c][m4..m4+3] (contiguous, 16B aligned)
    #pragma unroll 4
    for (int it = 0; it < 16; ++it) {
        int w = tid + it * 256;
        int c = w >> 5;
        int m4 = (w & 31) << 2;
        f32x4 o = *(const f32x4*)&T[c][m4];
        if (!diag) {
            __builtin_nontemporal_store(o, (f32x4*)&adj[(size_t)(j0 + c) * N + i0 + m4]);
        } else {
            #pragma unroll
            for (int e = 0; e < 4; ++e)
                if (m4 + e < c)
                    adj[(size_t)(j0 + c) * N + i0 + m4 + e] = o[e];
        }
    }
    if (diag && tid < 128) {
        float dm = drow[tid];
        adj[(size_t)(i0 + tid) * N + i0 + tid] = dm * dm;
    }
}

// ---------------------------------------------------------------------------
extern "C" void kernel_launch(void* const* d_in, const int* in_sizes, int n_in,
                              void* d_out, int out_size, void* d_ws, size_t ws_size,
                              hipStream_t stream)
{
    const float* h     = (const float*)d_in[0];
    const float* W1    = (const float*)d_in[1];
    const float* b1    = (const float*)d_in[2];
    const float* W2    = (const float*)d_in[3];
    const float* b2    = (const float*)d_in[4];
    const float* noise = (const float*)d_in[5];

    float* adj    = (float*)d_out;                 // output 0: adj_norm [N,N]
    float* logits = adj + (size_t)N * N;           // output 1: adj_logits [N,N]

    _Float16* Zf       = (_Float16*)d_ws;                      // 2 MiB
    unsigned char* vws = (unsigned char*)(Zf + (size_t)N * ZD);// 2080*16384 u8 = 34 MiB
    float* sums        = (float*)(vws + (size_t)NUPPER * 128 * 128); // [N]

    k1_mlp<<<256, 256, 0, stream>>>(h, W1, b1, W2, b2, Zf, sums);
    k3_main<<<NUPPER, 256, 0, stream>>>(Zf, noise, logits, vws, sums);
    k5_norm<<<NUPPER, 256, 0, stream>>>(vws, adj, sums);
}